// Round 1
// baseline (503.094 us; speedup 1.0000x reference)
//
#include <hip/hip_runtime.h>
#include <cmath>

// SoftmaxStable over N = 2^26 fp32 elements.
// 3 kernels: (1) online-softmax partials (read x once, fused max+sum),
//            (2) tiny partial reduce, (3) out = exp(x-m)*inv (read + write).
// HBM traffic = 3*256MB = 768MB -> ~122us floor at 6.3 TB/s.

#define BLOCK 256
#define NBLK  8192   // 2M threads; 64M elems / 4 (float4) / 2M = 8 iters/thread

// Numerically-safe combine of two (max, sum) online-softmax states.
// Guards m==mn so (-inf,-inf) never produces exp(nan).
__device__ __forceinline__ void combine(float& m, double& s, float m2, double s2) {
    float mn = fmaxf(m, m2);
    double e1 = (m  == mn) ? s  : s  * exp((double)(m  - mn));
    double e2 = (m2 == mn) ? s2 : s2 * exp((double)(m2 - mn));
    s = e1 + e2;
    m = mn;
}

__global__ __launch_bounds__(BLOCK)
void k_partials(const float4* __restrict__ x, long n4,
                double* __restrict__ ps, float* __restrict__ pm) {
    float  m = -INFINITY;
    double s = 0.0;
    long stride = (long)gridDim.x * BLOCK;
    for (long i = (long)blockIdx.x * BLOCK + threadIdx.x; i < n4; i += stride) {
        float4 v = x[i];
        float vm = fmaxf(fmaxf(v.x, v.y), fmaxf(v.z, v.w));
        if (vm > m) {
            // rescale existing sum to the new max (rare; fp64 for accuracy)
            s = (m == -INFINITY) ? 0.0 : s * exp((double)(m - vm));
            m = vm;
        }
        s += (double)__expf(v.x - m);
        s += (double)__expf(v.y - m);
        s += (double)__expf(v.z - m);
        s += (double)__expf(v.w - m);
    }
    // wave (64-lane) butterfly reduce
    for (int off = 32; off > 0; off >>= 1) {
        float  m2 = __shfl_down(m, off, 64);
        double s2 = __shfl_down(s, off, 64);
        combine(m, s, m2, s2);
    }
    __shared__ float  sm[BLOCK / 64];
    __shared__ double ss[BLOCK / 64];
    int lane = threadIdx.x & 63;
    int wid  = threadIdx.x >> 6;
    if (lane == 0) { sm[wid] = m; ss[wid] = s; }
    __syncthreads();
    if (threadIdx.x == 0) {
        for (int w = 1; w < BLOCK / 64; ++w) combine(m, s, sm[w], ss[w]);
        ps[blockIdx.x] = s;
        pm[blockIdx.x] = m;
    }
}

__global__ __launch_bounds__(1024)
void k_reduce(const double* __restrict__ ps, const float* __restrict__ pm,
              int nblk, float* __restrict__ fin) {
    float  m = -INFINITY;
    double s = 0.0;
    for (int i = threadIdx.x; i < nblk; i += 1024) combine(m, s, pm[i], ps[i]);
    for (int off = 32; off > 0; off >>= 1) {
        float  m2 = __shfl_down(m, off, 64);
        double s2 = __shfl_down(s, off, 64);
        combine(m, s, m2, s2);
    }
    __shared__ float  sm[16];
    __shared__ double ss[16];
    int lane = threadIdx.x & 63;
    int wid  = threadIdx.x >> 6;
    if (lane == 0) { sm[wid] = m; ss[wid] = s; }
    __syncthreads();
    if (threadIdx.x == 0) {
        for (int w = 1; w < 16; ++w) combine(m, s, sm[w], ss[w]);
        fin[0] = m;
        fin[1] = (float)(1.0 / s);   // reciprocal in fp64, cast once
    }
}

__global__ __launch_bounds__(BLOCK)
void k_out(const float4* __restrict__ x, float4* __restrict__ o, long n4,
           const float* __restrict__ fin) {
    float m   = fin[0];   // uniform -> scalar-cached load
    float inv = fin[1];
    long stride = (long)gridDim.x * BLOCK;
    for (long i = (long)blockIdx.x * BLOCK + threadIdx.x; i < n4; i += stride) {
        float4 v = x[i];
        float4 r;
        r.x = __expf(v.x - m) * inv;
        r.y = __expf(v.y - m) * inv;
        r.z = __expf(v.z - m) * inv;
        r.w = __expf(v.w - m) * inv;
        o[i] = r;
    }
}

extern "C" void kernel_launch(void* const* d_in, const int* in_sizes, int n_in,
                              void* d_out, int out_size, void* d_ws, size_t ws_size,
                              hipStream_t stream) {
    const float* x = (const float*)d_in[0];
    float* out = (float*)d_out;
    long n  = (long)in_sizes[0];
    long n4 = n / 4;                // N = 2^26, exactly divisible

    // ws layout: [NBLK doubles: s partials][NBLK floats: m partials][2 floats: m, inv]
    double* ps  = (double*)d_ws;
    float*  pm  = (float*)((char*)d_ws + NBLK * sizeof(double));
    float*  fin = (float*)((char*)d_ws + NBLK * (sizeof(double) + sizeof(float)));

    hipLaunchKernelGGL(k_partials, dim3(NBLK), dim3(BLOCK), 0, stream,
                       (const float4*)x, n4, ps, pm);
    hipLaunchKernelGGL(k_reduce, dim3(1), dim3(1024), 0, stream, ps, pm, NBLK, fin);
    hipLaunchKernelGGL(k_out, dim3(NBLK), dim3(BLOCK), 0, stream,
                       (const float4*)x, (float4*)out, n4, fin);
}

// Round 2
// 473.921 us; speedup vs baseline: 1.0616x; 1.0616x over previous
//
#include <hip/hip_runtime.h>
#include <cmath>

// SoftmaxStable over N = 2^26 fp32 elements.
// Pass 1: each thread registers-loads 32 elems, local max THEN fp32 exp-sum
//         (no online rescale, no fp64 exp anywhere) -> per-block (m, s) partials.
// Pass 2: tiny reduce of 8192 partials -> (m, 1/total).
// Pass 3: out = __expf(x-m)*inv with NON-TEMPORAL stores so x (exactly 256 MiB
//         = L3 size) stays L3-resident from pass 1 and the re-read hits L3.
// HBM floor: 256 rd + (256 rd, partially L3-absorbed) + 256 wr.

typedef float f4v __attribute__((ext_vector_type(4)));

#define BLOCK 256
#define NBLK  8192   // 8192 blk * 256 thr * 8 iter * float4 = 2^26 elems exactly
#define ITERS 8

// Combine two (max, sum) states; scale factor via fp32 __expf, sum in fp64.
// Guards m==mn so (-inf,-inf) never produces 0*inf or exp(nan).
__device__ __forceinline__ void combine(float& m, double& s, float m2, double s2) {
    float mn = fmaxf(m, m2);
    double e1 = (m  == mn) ? s  : s  * (double)__expf(m  - mn);
    double e2 = (m2 == mn) ? s2 : s2 * (double)__expf(m2 - mn);
    s = e1 + e2;
    m = mn;
}

__global__ __launch_bounds__(BLOCK)
void k_partials(const f4v* __restrict__ x, long n4,
                double* __restrict__ ps, float* __restrict__ pm) {
    // Block-contiguous chunk: 8 iters * 256 thr * 16B = 32 KB per block.
    long base = (long)blockIdx.x * (BLOCK * ITERS) + threadIdx.x;
    f4v v[ITERS];
#pragma unroll
    for (int j = 0; j < ITERS; ++j) {
        long idx = base + (long)j * BLOCK;
        if (idx < n4) v[j] = x[idx];
        else          v[j] = (f4v){-INFINITY, -INFINITY, -INFINITY, -INFINITY};
    }
    float m = -INFINITY;
#pragma unroll
    for (int j = 0; j < ITERS; ++j)
        m = fmaxf(m, fmaxf(fmaxf(v[j].x, v[j].y), fmaxf(v[j].z, v[j].w)));
    float s = 0.f;
    if (m != -INFINITY) {   // all-padding thread guard (never taken at N=2^26)
#pragma unroll
        for (int j = 0; j < ITERS; ++j)
            s += __expf(v[j].x - m) + __expf(v[j].y - m) +
                 __expf(v[j].z - m) + __expf(v[j].w - m);
    }
    double sd = (double)s;
    for (int off = 32; off > 0; off >>= 1) {   // 64-lane wave butterfly
        float  m2 = __shfl_down(m,  off, 64);
        double s2 = __shfl_down(sd, off, 64);
        combine(m, sd, m2, s2);
    }
    __shared__ float  sm[BLOCK / 64];
    __shared__ double ss[BLOCK / 64];
    int lane = threadIdx.x & 63;
    int wid  = threadIdx.x >> 6;
    if (lane == 0) { sm[wid] = m; ss[wid] = sd; }
    __syncthreads();
    if (threadIdx.x == 0) {
        for (int w = 1; w < BLOCK / 64; ++w) combine(m, sd, sm[w], ss[w]);
        ps[blockIdx.x] = sd;
        pm[blockIdx.x] = m;
    }
}

__global__ __launch_bounds__(1024)
void k_reduce(const double* __restrict__ ps, const float* __restrict__ pm,
              int nblk, float* __restrict__ fin) {
    float  m = -INFINITY;
    double s = 0.0;
    for (int i = threadIdx.x; i < nblk; i += 1024) combine(m, s, pm[i], ps[i]);
    for (int off = 32; off > 0; off >>= 1) {
        float  m2 = __shfl_down(m, off, 64);
        double s2 = __shfl_down(s, off, 64);
        combine(m, s, m2, s2);
    }
    __shared__ float  sm[16];
    __shared__ double ss[16];
    int lane = threadIdx.x & 63;
    int wid  = threadIdx.x >> 6;
    if (lane == 0) { sm[wid] = m; ss[wid] = s; }
    __syncthreads();
    if (threadIdx.x == 0) {
        for (int w = 1; w < 16; ++w) combine(m, s, sm[w], ss[w]);
        fin[0] = m;
        fin[1] = (float)(1.0 / s);   // reciprocal in fp64, cast once
    }
}

__global__ __launch_bounds__(BLOCK)
void k_out(const f4v* __restrict__ x, f4v* __restrict__ o, long n4,
           const float* __restrict__ fin) {
    float m   = fin[0];   // wave-uniform
    float inv = fin[1];
    long stride = (long)gridDim.x * BLOCK;
    for (long i = (long)blockIdx.x * BLOCK + threadIdx.x; i < n4; i += stride) {
        f4v v = x[i];     // normal load: want L3 hit on x from pass 1
        f4v r;
        r.x = __expf(v.x - m) * inv;
        r.y = __expf(v.y - m) * inv;
        r.z = __expf(v.z - m) * inv;
        r.w = __expf(v.w - m) * inv;
        __builtin_nontemporal_store(r, &o[i]);   // don't evict x from L3
    }
}

extern "C" void kernel_launch(void* const* d_in, const int* in_sizes, int n_in,
                              void* d_out, int out_size, void* d_ws, size_t ws_size,
                              hipStream_t stream) {
    const float* x = (const float*)d_in[0];
    float* out = (float*)d_out;
    long n  = (long)in_sizes[0];
    long n4 = n / 4;                // N = 2^26, exactly divisible

    // ws layout: [NBLK doubles: s partials][NBLK floats: m partials][2 floats]
    double* ps  = (double*)d_ws;
    float*  pm  = (float*)((char*)d_ws + NBLK * sizeof(double));
    float*  fin = (float*)((char*)d_ws + NBLK * (sizeof(double) + sizeof(float)));

    hipLaunchKernelGGL(k_partials, dim3(NBLK), dim3(BLOCK), 0, stream,
                       (const f4v*)x, n4, ps, pm);
    hipLaunchKernelGGL(k_reduce, dim3(1), dim3(1024), 0, stream, ps, pm, NBLK, fin);
    hipLaunchKernelGGL(k_out, dim3(NBLK), dim3(BLOCK), 0, stream,
                       (const f4v*)x, (f4v*)out, n4, fin);
}